// Round 18
// baseline (29.339 us; speedup 1.0000x reference)
//
#include <hip/hip_runtime.h>
#include <math.h>

#define D_IN  2048
#define D_OUT 8192

// R14 champion (24.99 us) restored, + one micro-lever: non-temporal x loads
// (x is 16 MB read-once; NT keeps the shared P/G/S/U tables hot in L2/L3).
// Ledger: P/G prefetch (+6%, R11), NT out-stores (R11), position-split
// radix-4 final exchange (+3%, R14), S/U prefetch after barrier #4 (null but
// harmless, R12/R14). Batching/pipelining/packing/occupancy all falsified.
//
// Structure: one row per 256-thread block (4 waves).
//   FWHT-2048 distributed (8/thread; DPP+permlane lane stages; 4-way LDS
//   combine), random gather (P/G in regs), FWHT-8192 32/thread in-wave
//   h=1..1024, final h=2048/4096 position-split radix-4 (16 b128/thread),
//   cos epilogue with NT stores. All butterflies exact lo+hi / lo-hi
//   (ascending h, reference fp32 association).
//
// LDS = single 32 KB buffer X:
//   [0:512)     float4: FWHT-2048 combine scratch
//   [1536:2048) float4: FWHT-2048 result "A" (live: store -> end of gather)
//   [0:2048)    float4: FWHT-8192 exchange (quarter w at [512w : 512w+512))
//
// DPP direction convention (GCN): row_ror:N => dst[i] = src[(i-N) mod 16].

#if __has_builtin(__builtin_amdgcn_permlane16_swap) && __has_builtin(__builtin_amdgcn_permlane32_swap)
#define HAVE_PLSWAP 1
#endif

typedef float f32x4 __attribute__((ext_vector_type(4)));

template<int CTRL>
__device__ __forceinline__ float dpp_full(float x) {
  int xi = __float_as_int(x);
  return __int_as_float(__builtin_amdgcn_update_dpp(xi, xi, CTRL, 0xF, 0xF, true));
}
// partner across lane-xor-4: ror:4 feeds banks {1,3} (bit2=1), ror:12 feeds {0,2}
__device__ __forceinline__ float dpp_xor4(float x) {
  int xi = __float_as_int(x);
  int r = __builtin_amdgcn_update_dpp(0, xi, 0x124, 0xF, 0xA, false);  // ror:4  -> banks 1,3
  r     = __builtin_amdgcn_update_dpp(r,  xi, 0x12C, 0xF, 0x5, false); // ror:12 -> banks 0,2
  return __int_as_float(r);
}
__device__ __forceinline__ void bfly_pl16(float& A, float& B, float sgn) {
#ifdef HAVE_PLSWAP
  auto r0 = __builtin_amdgcn_permlane16_swap(__float_as_uint(A), __float_as_uint(B), false, false);
  float lo = __uint_as_float(r0[0]), hi = __uint_as_float(r0[1]);
  float s = lo + hi, d = lo - hi;
  auto r1 = __builtin_amdgcn_permlane16_swap(__float_as_uint(s), __float_as_uint(d), false, false);
  A = __uint_as_float(r1[0]); B = __uint_as_float(r1[1]);
  (void)sgn;
#else
  float pA = __shfl_xor(A, 16, 64); A = fmaf(sgn, A, pA);
  float pB = __shfl_xor(B, 16, 64); B = fmaf(sgn, B, pB);
#endif
}
__device__ __forceinline__ void bfly_pl32(float& A, float& B, float sgn) {
#ifdef HAVE_PLSWAP
  auto r0 = __builtin_amdgcn_permlane32_swap(__float_as_uint(A), __float_as_uint(B), false, false);
  float lo = __uint_as_float(r0[0]), hi = __uint_as_float(r0[1]);
  float s = lo + hi, d = lo - hi;
  auto r1 = __builtin_amdgcn_permlane32_swap(__float_as_uint(s), __float_as_uint(d), false, false);
  A = __uint_as_float(r1[0]); B = __uint_as_float(r1[1]);
  (void)sgn;
#else
  float pA = __shfl_xor(A, 32, 64); A = fmaf(sgn, A, pA);
  float pB = __shfl_xor(B, 32, 64); B = fmaf(sgn, B, pB);
#endif
}

__global__ __launch_bounds__(256) void fastfood_kernel(
    const float* __restrict__ xg, const float* __restrict__ Bg,
    const float* __restrict__ Gg, const float* __restrict__ Sg,
    const int*   __restrict__ Pg, const float* __restrict__ Ug,
    float* __restrict__ outg)
{
  __shared__ float4 X4s[D_OUT / 4];   // 32 KB single buffer (see layout above)

  const int t = threadIdx.x, lane = t & 63, wave = t >> 6;
  const int row = blockIdx.x;
  const float sg1  = (lane & 1)  ? -1.f : 1.f;
  const float sg2  = (lane & 2)  ? -1.f : 1.f;
  const float sg4  = (lane & 4)  ? -1.f : 1.f;
  const float sg8  = (lane & 8)  ? -1.f : 1.f;
  const float sg16 = (lane & 16) ? -1.f : 1.f;
  const float sg32 = (lane & 32) ? -1.f : 1.f;
  // small-combine signs: u_m = fmaf(s0, own, pB); u_o = fmaf(s0, pC, pD);
  //                      res = fmaf(s1, u_m, u_o)
  const float s0w = (wave & 1) ? -1.f : 1.f;
  const float s1w = (wave & 2) ? -1.f : 1.f;

  // ===== FWHT-2048 of B*x, distributed: d = c | lane<<2 | m<<8 | wave<<9 =====
  float a[8];   // a[4m+c]
  {
    const f32x4* x4 = reinterpret_cast<const f32x4*>(xg + (size_t)row * D_IN);
    const float4* B4 = reinterpret_cast<const float4*>(Bg);
#pragma unroll
    for (int m = 0; m < 2; ++m) {
      int f = lane + 64 * m + 128 * wave;
      f32x4 xv = __builtin_nontemporal_load(&x4[f]);   // read-once stream
      float4 bv = B4[f];
      a[4*m+0] = xv[0] * bv.x; a[4*m+1] = xv[1] * bv.y;
      a[4*m+2] = xv[2] * bv.z; a[4*m+3] = xv[3] * bv.w;
    }
  }
  // Prefetch permutation + Gaussian scale (hide L2 latency under the compute)
  int4   pp[8];
  float4 gv[8];
  {
    const int4*   P4 = reinterpret_cast<const int4*>(Pg);
    const float4* G4 = reinterpret_cast<const float4*>(Gg);
#pragma unroll
    for (int q = 0; q < 8; ++q) {
      int idx = lane + 64 * q + 512 * wave;
      pp[q] = P4[idx];
      gv[q] = G4[idx];
    }
  }
#pragma unroll
  for (int m = 0; m < 2; ++m) {                                   // h=1,2
    float x0=a[4*m],x1=a[4*m+1],x2=a[4*m+2],x3=a[4*m+3];
    float y0=x0+x1,y1=x0-x1,y2=x2+x3,y3=x2-x3;
    a[4*m]=y0+y2; a[4*m+2]=y0-y2; a[4*m+1]=y1+y3; a[4*m+3]=y1-y3;
  }
#pragma unroll
  for (int k = 0; k < 8; ++k) { float p = dpp_full<0xB1>(a[k]);  a[k] = fmaf(sg1, a[k], p); }   // h=4
#pragma unroll
  for (int k = 0; k < 8; ++k) { float p = dpp_full<0x4E>(a[k]);  a[k] = fmaf(sg2, a[k], p); }   // h=8
#pragma unroll
  for (int k = 0; k < 8; ++k) { float p = dpp_xor4(a[k]);        a[k] = fmaf(sg4, a[k], p); }   // h=16
#pragma unroll
  for (int k = 0; k < 8; ++k) { float p = dpp_full<0x128>(a[k]); a[k] = fmaf(sg8, a[k], p); }   // h=32
#pragma unroll
  for (int k = 0; k < 8; k += 2) bfly_pl16(a[k], a[k+1], sg16);                                 // h=64
#pragma unroll
  for (int k = 0; k < 8; k += 2) bfly_pl32(a[k], a[k+1], sg32);                                 // h=128
#pragma unroll
  for (int c = 0; c < 4; ++c) {                                   // h=256 (m bit)
    float lo = a[c], hi = a[4+c];
    a[c] = lo + hi; a[4+c] = lo - hi;
  }
  // h=512,1024: 4-way cross-wave combine via scratch X[0:512)
#pragma unroll
  for (int m = 0; m < 2; ++m)
    X4s[lane + 64 * m + 128 * wave] = make_float4(a[4*m], a[4*m+1], a[4*m+2], a[4*m+3]);
  __syncthreads();   // #1 scratch ready
#pragma unroll
  for (int m = 0; m < 2; ++m) {
    int fb = lane + 64 * m;
    float4 B4v = X4s[fb + 128 * (wave ^ 1)];
    float4 C4v = X4s[fb + 128 * (wave ^ 2)];
    float4 D4v = X4s[fb + 128 * (wave ^ 3)];
    float pB[4] = {B4v.x, B4v.y, B4v.z, B4v.w};
    float pC[4] = {C4v.x, C4v.y, C4v.z, C4v.w};
    float pD[4] = {D4v.x, D4v.y, D4v.z, D4v.w};
#pragma unroll
    for (int c = 0; c < 4; ++c) {
      float um = fmaf(s0w, a[4*m+c], pB[c]);
      float uo = fmaf(s0w, pC[c], pD[c]);
      a[4*m+c] = fmaf(s1w, um, uo);
    }
  }
  // store final FWHT-2048 into A = X[1536:2048) (disjoint from scratch [0:512))
#pragma unroll
  for (int m = 0; m < 2; ++m)
    X4s[1536 + lane + 64 * m + 128 * wave] = make_float4(a[4*m], a[4*m+1], a[4*m+2], a[4*m+3]);
  __syncthreads();   // #2 A ready

  // ===== gather + Gaussian scale: o = c | lane<<2 | q<<8 | wave<<11 =====
  float v[32];
  {
    const float* a_f = reinterpret_cast<const float*>(X4s + 1536);
#pragma unroll
    for (int q = 0; q < 8; ++q) {
      v[4*q+0] = a_f[pp[q].x & (D_IN-1)] * gv[q].x;
      v[4*q+1] = a_f[pp[q].y & (D_IN-1)] * gv[q].y;
      v[4*q+2] = a_f[pp[q].z & (D_IN-1)] * gv[q].z;
      v[4*q+3] = a_f[pp[q].w & (D_IN-1)] * gv[q].w;
    }
  }

  // ===== FWHT-8192: h=1,2 (reg), h=4..128 (lane), h=256..1024 (q) =====
#pragma unroll
  for (int q = 0; q < 8; ++q) {
    float x0=v[4*q],x1=v[4*q+1],x2=v[4*q+2],x3=v[4*q+3];
    float y0=x0+x1,y1=x0-x1,y2=x2+x3,y3=x2-x3;
    v[4*q]=y0+y2; v[4*q+2]=y0-y2; v[4*q+1]=y1+y3; v[4*q+3]=y1-y3;
  }
#pragma unroll
  for (int k = 0; k < 32; ++k) { float p = dpp_full<0xB1>(v[k]);  v[k] = fmaf(sg1, v[k], p); }  // h=4
#pragma unroll
  for (int k = 0; k < 32; ++k) { float p = dpp_full<0x4E>(v[k]);  v[k] = fmaf(sg2, v[k], p); }  // h=8
#pragma unroll
  for (int k = 0; k < 32; ++k) { float p = dpp_xor4(v[k]);        v[k] = fmaf(sg4, v[k], p); }  // h=16
#pragma unroll
  for (int k = 0; k < 32; ++k) { float p = dpp_full<0x128>(v[k]); v[k] = fmaf(sg8, v[k], p); }  // h=32
#pragma unroll
  for (int k = 0; k < 32; k += 2) bfly_pl16(v[k], v[k+1], sg16);                                // h=64
#pragma unroll
  for (int k = 0; k < 32; k += 2) bfly_pl32(v[k], v[k+1], sg32);                                // h=128
#pragma unroll
  for (int b = 1; b < 8; b <<= 1)                                                               // h=256,512,1024
#pragma unroll
    for (int q = 0; q < 8; ++q) if (!(q & b))
#pragma unroll
      for (int c = 0; c < 4; ++c) {
        float lo = v[4*q+c], hi = v[4*(q|b)+c];
        v[4*q+c] = lo + hi; v[4*(q|b)+c] = lo - hi;
      }

  __syncthreads();   // #3 gather reads of A complete -> X fully reusable

  // ===== h=2048,4096: position-split radix-4 across waves =====
  // write own quarter: X4s[p + 512*wave], p = lane + 64*q  (pos p of quarter `wave`)
#pragma unroll
  for (int q = 0; q < 8; ++q)
    X4s[lane + 64 * q + 512 * wave] = make_float4(v[4*q], v[4*q+1], v[4*q+2], v[4*q+3]);
  __syncthreads();   // #4 exchange ready

  // Prefetch S/U for the output mapping (latency hides under the reads below)
  float4 s4r[8], u4r[8];
  {
    const float4* S4 = reinterpret_cast<const float4*>(Sg);
    const float4* U4 = reinterpret_cast<const float4*>(Ug);
#pragma unroll
    for (int q = 0; q < 4; ++q)
#pragma unroll
      for (int j = 0; j < 2; ++j) {
        int idx = (q << 9) + 128 * wave + 64 * j + lane;
        s4r[2*q+j] = S4[idx];
        u4r[2*q+j] = U4[idx];
      }
  }

  // wave w handles positions [128w, 128w+128): per thread j=0,1 -> pos = 128w+64j+lane.
  // Reads 4 quarters at pos (8 b128), computes all 4 quarters' outputs (radix-4).
  float o[4][2][4];   // [quarter][j][component]
#pragma unroll
  for (int j = 0; j < 2; ++j) {
    int pos = 128 * wave + 64 * j + lane;
    float4 i0 = X4s[pos];
    float4 i1 = X4s[512 + pos];
    float4 i2 = X4s[1024 + pos];
    float4 i3 = X4s[1536 + pos];
    float q0[4] = {i0.x, i0.y, i0.z, i0.w};
    float q1[4] = {i1.x, i1.y, i1.z, i1.w};
    float q2[4] = {i2.x, i2.y, i2.z, i2.w};
    float q3[4] = {i3.x, i3.y, i3.z, i3.w};
#pragma unroll
    for (int c = 0; c < 4; ++c) {
      float y0 = q0[c] + q1[c], y1 = q0[c] - q1[c];   // h=2048: pairs (0,1),(2,3)
      float y2 = q2[c] + q3[c], y3 = q2[c] - q3[c];
      o[0][j][c] = y0 + y2; o[2][j][c] = y0 - y2;     // h=4096: pairs (0,2),(1,3)
      o[1][j][c] = y1 + y3; o[3][j][c] = y1 - y3;
    }
  }

  // ===== epilogue: cos(Vx + 2*pi*U) * sqrt(2/O), non-temporal stores =====
  {
    const float c1 = (float)(1.0 / (6.283185307179586 * 90.50966799187808)); // 1/(2*pi*sqrt(8192))
    f32x4* out4 = reinterpret_cast<f32x4*>(outg + (size_t)row * D_OUT);
#pragma unroll
    for (int q = 0; q < 4; ++q)
#pragma unroll
      for (int j = 0; j < 2; ++j) {
        int idx = (q << 9) + 128 * wave + 64 * j + lane;
        float4 s4 = s4r[2*q+j], u4 = u4r[2*q+j];
        f32x4 res;
        float rev;
        rev = fmaf(o[q][j][0]*s4.x, c1, u4.x); rev -= rintf(rev); res[0] = __builtin_amdgcn_cosf(rev) * 0.015625f;
        rev = fmaf(o[q][j][1]*s4.y, c1, u4.y); rev -= rintf(rev); res[1] = __builtin_amdgcn_cosf(rev) * 0.015625f;
        rev = fmaf(o[q][j][2]*s4.z, c1, u4.z); rev -= rintf(rev); res[2] = __builtin_amdgcn_cosf(rev) * 0.015625f;
        rev = fmaf(o[q][j][3]*s4.w, c1, u4.w); rev -= rintf(rev); res[3] = __builtin_amdgcn_cosf(rev) * 0.015625f;
        __builtin_nontemporal_store(res, &out4[idx]);
      }
  }
}

extern "C" void kernel_launch(void* const* d_in, const int* in_sizes, int n_in,
                              void* d_out, int out_size, void* d_ws, size_t ws_size,
                              hipStream_t stream) {
  const float* x = (const float*)d_in[0];
  const float* B = (const float*)d_in[1];
  const float* G = (const float*)d_in[2];
  const float* S = (const float*)d_in[3];
  const int*   P = (const int*)d_in[4];
  const float* U = (const float*)d_in[5];
  float* out = (float*)d_out;
  const int rows = in_sizes[0] / D_IN;  // 2048
  fastfood_kernel<<<rows, 256, 0, stream>>>(x, B, G, S, P, U, out);
}

// Round 19
// 24.965 us; speedup vs baseline: 1.1752x; 1.1752x over previous
//
#include <hip/hip_runtime.h>
#include <math.h>

#define D_IN  2048
#define D_OUT 8192

// CHAMPION (R14, 24.99 us) — final form. One row per 256-thread block (4 waves).
//   FWHT-2048 distributed (8/thread; DPP+permlane lane stages; 4-way LDS
//   combine), random gather (P/G prefetched at kernel start, +6% R11),
//   FWHT-8192 32/thread in-wave h=1..1024, final h=2048/4096 position-split
//   radix-4 (16 b128/thread, +3% R14), cos epilogue with NT stores.
//   All butterflies exact lo+hi / lo-hi (ascending h, reference association).
// Falsified levers (A/B): occupancy +-1 blk, S/U-prefetch timing, fp32
// packing, in-block pipelining, row batching r={2,4}, NT x-loads.
//
// LDS = single 32 KB buffer X:
//   [0:512)     float4: FWHT-2048 combine scratch
//   [1536:2048) float4: FWHT-2048 result "A" (live: store -> end of gather)
//   [0:2048)    float4: FWHT-8192 exchange (quarter w at [512w : 512w+512))
//
// DPP direction convention (GCN): row_ror:N => dst[i] = src[(i-N) mod 16].

#if __has_builtin(__builtin_amdgcn_permlane16_swap) && __has_builtin(__builtin_amdgcn_permlane32_swap)
#define HAVE_PLSWAP 1
#endif

typedef float f32x4 __attribute__((ext_vector_type(4)));

template<int CTRL>
__device__ __forceinline__ float dpp_full(float x) {
  int xi = __float_as_int(x);
  return __int_as_float(__builtin_amdgcn_update_dpp(xi, xi, CTRL, 0xF, 0xF, true));
}
// partner across lane-xor-4: ror:4 feeds banks {1,3} (bit2=1), ror:12 feeds {0,2}
__device__ __forceinline__ float dpp_xor4(float x) {
  int xi = __float_as_int(x);
  int r = __builtin_amdgcn_update_dpp(0, xi, 0x124, 0xF, 0xA, false);  // ror:4  -> banks 1,3
  r     = __builtin_amdgcn_update_dpp(r,  xi, 0x12C, 0xF, 0x5, false); // ror:12 -> banks 0,2
  return __int_as_float(r);
}
__device__ __forceinline__ void bfly_pl16(float& A, float& B, float sgn) {
#ifdef HAVE_PLSWAP
  auto r0 = __builtin_amdgcn_permlane16_swap(__float_as_uint(A), __float_as_uint(B), false, false);
  float lo = __uint_as_float(r0[0]), hi = __uint_as_float(r0[1]);
  float s = lo + hi, d = lo - hi;
  auto r1 = __builtin_amdgcn_permlane16_swap(__float_as_uint(s), __float_as_uint(d), false, false);
  A = __uint_as_float(r1[0]); B = __uint_as_float(r1[1]);
  (void)sgn;
#else
  float pA = __shfl_xor(A, 16, 64); A = fmaf(sgn, A, pA);
  float pB = __shfl_xor(B, 16, 64); B = fmaf(sgn, B, pB);
#endif
}
__device__ __forceinline__ void bfly_pl32(float& A, float& B, float sgn) {
#ifdef HAVE_PLSWAP
  auto r0 = __builtin_amdgcn_permlane32_swap(__float_as_uint(A), __float_as_uint(B), false, false);
  float lo = __uint_as_float(r0[0]), hi = __uint_as_float(r0[1]);
  float s = lo + hi, d = lo - hi;
  auto r1 = __builtin_amdgcn_permlane32_swap(__float_as_uint(s), __float_as_uint(d), false, false);
  A = __uint_as_float(r1[0]); B = __uint_as_float(r1[1]);
  (void)sgn;
#else
  float pA = __shfl_xor(A, 32, 64); A = fmaf(sgn, A, pA);
  float pB = __shfl_xor(B, 32, 64); B = fmaf(sgn, B, pB);
#endif
}

__global__ __launch_bounds__(256) void fastfood_kernel(
    const float* __restrict__ xg, const float* __restrict__ Bg,
    const float* __restrict__ Gg, const float* __restrict__ Sg,
    const int*   __restrict__ Pg, const float* __restrict__ Ug,
    float* __restrict__ outg)
{
  __shared__ float4 X4s[D_OUT / 4];   // 32 KB single buffer (see layout above)

  const int t = threadIdx.x, lane = t & 63, wave = t >> 6;
  const int row = blockIdx.x;
  const float sg1  = (lane & 1)  ? -1.f : 1.f;
  const float sg2  = (lane & 2)  ? -1.f : 1.f;
  const float sg4  = (lane & 4)  ? -1.f : 1.f;
  const float sg8  = (lane & 8)  ? -1.f : 1.f;
  const float sg16 = (lane & 16) ? -1.f : 1.f;
  const float sg32 = (lane & 32) ? -1.f : 1.f;
  // small-combine signs: u_m = fmaf(s0, own, pB); u_o = fmaf(s0, pC, pD);
  //                      res = fmaf(s1, u_m, u_o)
  const float s0w = (wave & 1) ? -1.f : 1.f;
  const float s1w = (wave & 2) ? -1.f : 1.f;

  // ===== FWHT-2048 of B*x, distributed: d = c | lane<<2 | m<<8 | wave<<9 =====
  float a[8];   // a[4m+c]
  {
    const float4* x4 = reinterpret_cast<const float4*>(xg + (size_t)row * D_IN);
    const float4* B4 = reinterpret_cast<const float4*>(Bg);
#pragma unroll
    for (int m = 0; m < 2; ++m) {
      int f = lane + 64 * m + 128 * wave;
      float4 xv = x4[f], bv = B4[f];
      a[4*m+0] = xv.x * bv.x; a[4*m+1] = xv.y * bv.y;
      a[4*m+2] = xv.z * bv.z; a[4*m+3] = xv.w * bv.w;
    }
  }
  // Prefetch permutation + Gaussian scale (hide L2 latency under the compute)
  int4   pp[8];
  float4 gv[8];
  {
    const int4*   P4 = reinterpret_cast<const int4*>(Pg);
    const float4* G4 = reinterpret_cast<const float4*>(Gg);
#pragma unroll
    for (int q = 0; q < 8; ++q) {
      int idx = lane + 64 * q + 512 * wave;
      pp[q] = P4[idx];
      gv[q] = G4[idx];
    }
  }
#pragma unroll
  for (int m = 0; m < 2; ++m) {                                   // h=1,2
    float x0=a[4*m],x1=a[4*m+1],x2=a[4*m+2],x3=a[4*m+3];
    float y0=x0+x1,y1=x0-x1,y2=x2+x3,y3=x2-x3;
    a[4*m]=y0+y2; a[4*m+2]=y0-y2; a[4*m+1]=y1+y3; a[4*m+3]=y1-y3;
  }
#pragma unroll
  for (int k = 0; k < 8; ++k) { float p = dpp_full<0xB1>(a[k]);  a[k] = fmaf(sg1, a[k], p); }   // h=4
#pragma unroll
  for (int k = 0; k < 8; ++k) { float p = dpp_full<0x4E>(a[k]);  a[k] = fmaf(sg2, a[k], p); }   // h=8
#pragma unroll
  for (int k = 0; k < 8; ++k) { float p = dpp_xor4(a[k]);        a[k] = fmaf(sg4, a[k], p); }   // h=16
#pragma unroll
  for (int k = 0; k < 8; ++k) { float p = dpp_full<0x128>(a[k]); a[k] = fmaf(sg8, a[k], p); }   // h=32
#pragma unroll
  for (int k = 0; k < 8; k += 2) bfly_pl16(a[k], a[k+1], sg16);                                 // h=64
#pragma unroll
  for (int k = 0; k < 8; k += 2) bfly_pl32(a[k], a[k+1], sg32);                                 // h=128
#pragma unroll
  for (int c = 0; c < 4; ++c) {                                   // h=256 (m bit)
    float lo = a[c], hi = a[4+c];
    a[c] = lo + hi; a[4+c] = lo - hi;
  }
  // h=512,1024: 4-way cross-wave combine via scratch X[0:512)
#pragma unroll
  for (int m = 0; m < 2; ++m)
    X4s[lane + 64 * m + 128 * wave] = make_float4(a[4*m], a[4*m+1], a[4*m+2], a[4*m+3]);
  __syncthreads();   // #1 scratch ready
#pragma unroll
  for (int m = 0; m < 2; ++m) {
    int fb = lane + 64 * m;
    float4 B4v = X4s[fb + 128 * (wave ^ 1)];
    float4 C4v = X4s[fb + 128 * (wave ^ 2)];
    float4 D4v = X4s[fb + 128 * (wave ^ 3)];
    float pB[4] = {B4v.x, B4v.y, B4v.z, B4v.w};
    float pC[4] = {C4v.x, C4v.y, C4v.z, C4v.w};
    float pD[4] = {D4v.x, D4v.y, D4v.z, D4v.w};
#pragma unroll
    for (int c = 0; c < 4; ++c) {
      float um = fmaf(s0w, a[4*m+c], pB[c]);
      float uo = fmaf(s0w, pC[c], pD[c]);
      a[4*m+c] = fmaf(s1w, um, uo);
    }
  }
  // store final FWHT-2048 into A = X[1536:2048) (disjoint from scratch [0:512))
#pragma unroll
  for (int m = 0; m < 2; ++m)
    X4s[1536 + lane + 64 * m + 128 * wave] = make_float4(a[4*m], a[4*m+1], a[4*m+2], a[4*m+3]);
  __syncthreads();   // #2 A ready

  // ===== gather + Gaussian scale: o = c | lane<<2 | q<<8 | wave<<11 =====
  float v[32];
  {
    const float* a_f = reinterpret_cast<const float*>(X4s + 1536);
#pragma unroll
    for (int q = 0; q < 8; ++q) {
      v[4*q+0] = a_f[pp[q].x & (D_IN-1)] * gv[q].x;
      v[4*q+1] = a_f[pp[q].y & (D_IN-1)] * gv[q].y;
      v[4*q+2] = a_f[pp[q].z & (D_IN-1)] * gv[q].z;
      v[4*q+3] = a_f[pp[q].w & (D_IN-1)] * gv[q].w;
    }
  }

  // ===== FWHT-8192: h=1,2 (reg), h=4..128 (lane), h=256..1024 (q) =====
#pragma unroll
  for (int q = 0; q < 8; ++q) {
    float x0=v[4*q],x1=v[4*q+1],x2=v[4*q+2],x3=v[4*q+3];
    float y0=x0+x1,y1=x0-x1,y2=x2+x3,y3=x2-x3;
    v[4*q]=y0+y2; v[4*q+2]=y0-y2; v[4*q+1]=y1+y3; v[4*q+3]=y1-y3;
  }
#pragma unroll
  for (int k = 0; k < 32; ++k) { float p = dpp_full<0xB1>(v[k]);  v[k] = fmaf(sg1, v[k], p); }  // h=4
#pragma unroll
  for (int k = 0; k < 32; ++k) { float p = dpp_full<0x4E>(v[k]);  v[k] = fmaf(sg2, v[k], p); }  // h=8
#pragma unroll
  for (int k = 0; k < 32; ++k) { float p = dpp_xor4(v[k]);        v[k] = fmaf(sg4, v[k], p); }  // h=16
#pragma unroll
  for (int k = 0; k < 32; ++k) { float p = dpp_full<0x128>(v[k]); v[k] = fmaf(sg8, v[k], p); }  // h=32
#pragma unroll
  for (int k = 0; k < 32; k += 2) bfly_pl16(v[k], v[k+1], sg16);                                // h=64
#pragma unroll
  for (int k = 0; k < 32; k += 2) bfly_pl32(v[k], v[k+1], sg32);                                // h=128
#pragma unroll
  for (int b = 1; b < 8; b <<= 1)                                                               // h=256,512,1024
#pragma unroll
    for (int q = 0; q < 8; ++q) if (!(q & b))
#pragma unroll
      for (int c = 0; c < 4; ++c) {
        float lo = v[4*q+c], hi = v[4*(q|b)+c];
        v[4*q+c] = lo + hi; v[4*(q|b)+c] = lo - hi;
      }

  __syncthreads();   // #3 gather reads of A complete -> X fully reusable

  // ===== h=2048,4096: position-split radix-4 across waves =====
  // write own quarter: X4s[p + 512*wave], p = lane + 64*q  (pos p of quarter `wave`)
#pragma unroll
  for (int q = 0; q < 8; ++q)
    X4s[lane + 64 * q + 512 * wave] = make_float4(v[4*q], v[4*q+1], v[4*q+2], v[4*q+3]);
  __syncthreads();   // #4 exchange ready

  // Prefetch S/U for the output mapping (latency hides under the reads below)
  float4 s4r[8], u4r[8];
  {
    const float4* S4 = reinterpret_cast<const float4*>(Sg);
    const float4* U4 = reinterpret_cast<const float4*>(Ug);
#pragma unroll
    for (int q = 0; q < 4; ++q)
#pragma unroll
      for (int j = 0; j < 2; ++j) {
        int idx = (q << 9) + 128 * wave + 64 * j + lane;
        s4r[2*q+j] = S4[idx];
        u4r[2*q+j] = U4[idx];
      }
  }

  // wave w handles positions [128w, 128w+128): per thread j=0,1 -> pos = 128w+64j+lane.
  // Reads 4 quarters at pos (8 b128), computes all 4 quarters' outputs (radix-4).
  float o[4][2][4];   // [quarter][j][component]
#pragma unroll
  for (int j = 0; j < 2; ++j) {
    int pos = 128 * wave + 64 * j + lane;
    float4 i0 = X4s[pos];
    float4 i1 = X4s[512 + pos];
    float4 i2 = X4s[1024 + pos];
    float4 i3 = X4s[1536 + pos];
    float q0[4] = {i0.x, i0.y, i0.z, i0.w};
    float q1[4] = {i1.x, i1.y, i1.z, i1.w};
    float q2[4] = {i2.x, i2.y, i2.z, i2.w};
    float q3[4] = {i3.x, i3.y, i3.z, i3.w};
#pragma unroll
    for (int c = 0; c < 4; ++c) {
      float y0 = q0[c] + q1[c], y1 = q0[c] - q1[c];   // h=2048: pairs (0,1),(2,3)
      float y2 = q2[c] + q3[c], y3 = q2[c] - q3[c];
      o[0][j][c] = y0 + y2; o[2][j][c] = y0 - y2;     // h=4096: pairs (0,2),(1,3)
      o[1][j][c] = y1 + y3; o[3][j][c] = y1 - y3;
    }
  }

  // ===== epilogue: cos(Vx + 2*pi*U) * sqrt(2/O), non-temporal stores =====
  {
    const float c1 = (float)(1.0 / (6.283185307179586 * 90.50966799187808)); // 1/(2*pi*sqrt(8192))
    f32x4* out4 = reinterpret_cast<f32x4*>(outg + (size_t)row * D_OUT);
#pragma unroll
    for (int q = 0; q < 4; ++q)
#pragma unroll
      for (int j = 0; j < 2; ++j) {
        int idx = (q << 9) + 128 * wave + 64 * j + lane;
        float4 s4 = s4r[2*q+j], u4 = u4r[2*q+j];
        f32x4 res;
        float rev;
        rev = fmaf(o[q][j][0]*s4.x, c1, u4.x); rev -= rintf(rev); res[0] = __builtin_amdgcn_cosf(rev) * 0.015625f;
        rev = fmaf(o[q][j][1]*s4.y, c1, u4.y); rev -= rintf(rev); res[1] = __builtin_amdgcn_cosf(rev) * 0.015625f;
        rev = fmaf(o[q][j][2]*s4.z, c1, u4.z); rev -= rintf(rev); res[2] = __builtin_amdgcn_cosf(rev) * 0.015625f;
        rev = fmaf(o[q][j][3]*s4.w, c1, u4.w); rev -= rintf(rev); res[3] = __builtin_amdgcn_cosf(rev) * 0.015625f;
        __builtin_nontemporal_store(res, &out4[idx]);
      }
  }
}

extern "C" void kernel_launch(void* const* d_in, const int* in_sizes, int n_in,
                              void* d_out, int out_size, void* d_ws, size_t ws_size,
                              hipStream_t stream) {
  const float* x = (const float*)d_in[0];
  const float* B = (const float*)d_in[1];
  const float* G = (const float*)d_in[2];
  const float* S = (const float*)d_in[3];
  const int*   P = (const int*)d_in[4];
  const float* U = (const float*)d_in[5];
  float* out = (float*)d_out;
  const int rows = in_sizes[0] / D_IN;  // 2048
  fastfood_kernel<<<rows, 256, 0, stream>>>(x, B, G, S, P, U, out);
}